// Round 9
// baseline (242.127 us; speedup 1.0000x reference)
//
#include <hip/hip_runtime.h>

// DeformConv fused pipeline, MI355X gfx950. Shapes: B=2, Ci=Co=256, H=W=96.
// R9 changes vs R8 (sample_s 100us latency-bound: 18 gathers consumed in-iter):
//  - sample_s: k-OUTER loop -> 16 independent gathers per k-pass (MLP=16),
//    pkw[36] zero-init+OR (parity trick was buggy across cl boundary),
//    launch_bounds(512,4).
//  - bn_stats: two-stage (1024 partial blocks + finalize) replaces 1-block/CU.

typedef unsigned short ushort_t;
typedef unsigned int uint_t;
typedef __attribute__((ext_vector_type(8))) short bf16x8;
typedef __attribute__((ext_vector_type(4))) float f32x4;
typedef __attribute__((ext_vector_type(2), aligned(4))) float f32x2a;

#define HH 96
#define WW 96
#define HWSZ 9216
#define CI 256
#define CO 256
#define NB 2
#define NPIX 18432
#define KTOT 2304

__device__ __forceinline__ ushort_t f2bf(float f) {
  unsigned int u = __float_as_uint(f);
  u += 0x7fffu + ((u >> 16) & 1u);
  return (ushort_t)(u >> 16);
}
__device__ __forceinline__ float u2f(uint_t u) { return __uint_as_float(u); }

__device__ __forceinline__ void gload16(const void* g, void* l) {
  __builtin_amdgcn_global_load_lds(
      (const __attribute__((address_space(1))) unsigned int*)g,
      (__attribute__((address_space(3))) unsigned int*)l, 16, 0, 0);
}

// ---------------- cvt_w9: w_dcn -> bf16 [kk>>3][m][kk&7] ----------------
__global__ void cvt_w9(const float* __restrict__ w, ushort_t* __restrict__ o) {
  int i = blockIdx.x * 256 + threadIdx.x;      // grid exact CO*KTOT
  int oo = i / KTOT;
  int kk = i - oo * KTOT;
  o[(kk >> 3) * 2048 + oo * 8 + (kk & 7)] = f2bf(w[i]);
}

// ---------------- cvt_woff9: w_off -> bf16 [kk>>3][m32][kk&7], rows>=27 zero ----
__global__ void cvt_woff9(const float* __restrict__ w, ushort_t* __restrict__ o) {
  int i = blockIdx.x * 256 + threadIdx.x;      // grid exact 32*KTOT
  int m = i / KTOT;
  int kk = i - m * KTOT;
  float v = (m < 27) ? w[m * KTOT + kk] : 0.f;
  o[(kk >> 3) * 256 + m * 8 + (kk & 7)] = f2bf(v);
}

// ---------------- off_gemm: om[27][NPIX] = W27 * im2col(x) ----------------
__global__ __launch_bounds__(512, 2) void off_gemm(
    const float* __restrict__ x, const ushort_t* __restrict__ w27r,
    float* __restrict__ om) {
  __shared__ __align__(16) ushort_t A27[2][2048];
  __shared__ __align__(16) ushort_t B64[2][4096];
  __shared__ uint2 tbl[9][64];                 // {abs idx (0 if invalid), mask}

  const int tid = threadIdx.x;
  const int lane = tid & 63, wid = tid >> 6;
  const int p0 = blockIdx.x * 64;
  const int bimg = p0 / HWSZ;
  const int hw0 = p0 - bimg * HWSZ;
  const float* xb = x + (size_t)bimg * CI * HWSZ;

  for (int e = tid; e < 576; e += 512) {
    int k = e >> 6, px = e & 63;
    int hw = hw0 + px, h = hw / WW, w_ = hw - h * WW;
    int dy = k / 3 - 1, dx = k % 3 - 1;
    bool ok = (h + dy >= 0) && (h + dy < HH) && (w_ + dx >= 0) && (w_ + dx < WW);
    tbl[k][px] = make_uint2(ok ? (uint_t)(hw + dy * WW + dx) : 0u,
                            ok ? 0x3f800000u : 0u);
  }

  const int lg = lane >> 4, lm = lane & 15;
  const int wr = wid >> 2, wc = wid & 3;
  f32x4 acc = (f32x4){0.f, 0.f, 0.f, 0.f};

  int cj[8], kj[8];
#pragma unroll
  for (int j = 0; j < 8; ++j) {
    int kk = wid * 8 + j;
    cj[j] = kk / 9;
    kj[j] = kk - 9 * cj[j];
  }
  __syncthreads();

#define OG_STAGE(CH, BUF)                                                     \
  {                                                                           \
    float raw[8], mkk[8];                                                     \
    _Pragma("unroll") for (int j = 0; j < 8; ++j) {                           \
      uint2 e_ = tbl[kj[j]][lane];                                            \
      raw[j] = xb[cj[j] * HWSZ + (int)e_.x];                                  \
      mkk[j] = u2f(e_.y);                                                     \
      kj[j] += 1; cj[j] += 7;                                                 \
      if (kj[j] == 9) { kj[j] = 0; cj[j] += 1; }                              \
    }                                                                         \
    gload16(w27r + (size_t)(CH) * 2048 + (tid & 255) * 8,                     \
            &A27[BUF][(wid & 3) * 512]);                                      \
    ushort_t sv_[8] __attribute__((aligned(16)));                             \
    _Pragma("unroll") for (int j = 0; j < 8; ++j) sv_[j] = f2bf(raw[j] * mkk[j]); \
    *(uint4*)&B64[BUF][tid * 8] = *(const uint4*)sv_;                         \
  }

  OG_STAGE(0, 0)
  for (int ko = 0; ko < 36; ++ko) {
    const int cur = ko & 1, nxt = cur ^ 1;
    if (ko < 35) OG_STAGE(ko + 1, nxt)
    asm volatile("s_waitcnt vmcnt(0) lgkmcnt(0)" ::: "memory");
    __builtin_amdgcn_s_barrier();
    __builtin_amdgcn_sched_barrier(0);
#pragma unroll
    for (int s = 0; s < 2; ++s) {
      bf16x8 af = *(const bf16x8*)&A27[cur][((s * 4 + lg) * 32 + wr * 16 + lm) * 8];
      bf16x8 bfv = *(const bf16x8*)&B64[cur][((s * 4 + lg) * 64 + wc * 16 + lm) * 8];
      acc = __builtin_amdgcn_mfma_f32_16x16x32_bf16(af, bfv, acc, 0, 0, 0);
    }
    asm volatile("s_waitcnt lgkmcnt(0)" ::: "memory");
    __builtin_amdgcn_s_barrier();
    __builtin_amdgcn_sched_barrier(0);
  }
#undef OG_STAGE

  int row = wr * 16 + lg * 4;
  int col = p0 + wc * 16 + lm;
#pragma unroll
  for (int r = 0; r < 4; ++r)
    if (row + r < 27) om[(size_t)(row + r) * NPIX + col] = acc[r];
}

// ---------------- prep: om -> row-pair offsets + folded weights ----------------
__global__ void prep_kernel(const float* __restrict__ om, const float* __restrict__ b_off,
                            uint_t* __restrict__ offs, float4* __restrict__ wts) {
  int n = blockIdx.x * 128 + threadIdx.x;      // grid 144 x 128
  float omv[27];
#pragma unroll
  for (int ch = 0; ch < 27; ++ch) omv[ch] = b_off[ch] + om[(size_t)ch * NPIX + n];
  int hw = n % HWSZ;
  int h = hw / WW, w = hw - h * WW;
#pragma unroll
  for (int k = 0; k < 9; ++k) {
    float dy = omv[2 * k], dx = omv[2 * k + 1];
    float mk = 1.f / (1.f + __expf(-omv[18 + k]));
    float py = dy + (float)(h - 1 + k / 3);
    float px = dx + (float)(w - 1 + k % 3);
    float y0f = floorf(py), x0f = floorf(px);
    int y0 = (int)y0f, x0 = (int)x0f;
    float wy1 = py - y0f, wx1 = px - x0f;
    float wy0 = 1.f - wy1, wx0 = 1.f - wx1;
    float vy0 = (y0 >= 0 && y0 <= HH - 1) ? 1.f : 0.f;
    float vy1 = (y0 + 1 >= 0 && y0 + 1 <= HH - 1) ? 1.f : 0.f;
    int yc0 = min(max(y0, 0), HH - 1), yc1 = min(max(y0 + 1, 0), HH - 1);
    int xa = min(max(x0, 0), WW - 2);
    float a_, b_;
    if (x0 >= 0 && x0 <= WW - 2)      { a_ = wx0; b_ = wx1; }
    else if (x0 == -1)                { a_ = wx1; b_ = 0.f; }
    else if (x0 == WW - 1)            { a_ = 0.f; b_ = wx0; }
    else                              { a_ = 0.f; b_ = 0.f; }
    float s0 = mk * vy0 * wy0, s1 = mk * vy1 * wy1;
    offs[(size_t)k * NPIX + n] = (uint_t)(yc0 * WW + xa) | ((uint_t)(yc1 * WW + xa) << 16);
    wts[(size_t)k * NPIX + n] = make_float4(a_ * s0, b_ * s0, a_ * s1, b_ * s1);
  }
}

// ---------------- sample_s: S_g[kk>>3][n][kk&7] bf16 ----------------
// Grid 288 x 4 (channel quarters); wave = 8 channels. k-OUTER: per k-pass one
// (off,wt) in regs + 16 independent gathers (MLP). pkw zero-init + OR.
__global__ __launch_bounds__(512, 4) void sample_s(
    const float* __restrict__ x, const uint_t* __restrict__ offs,
    const float4* __restrict__ wts, ushort_t* __restrict__ S_g) {
  const int tid = threadIdx.x;
  const int lane = tid & 63, wid = tid >> 6;
  const int p0 = blockIdx.x * 64;
  const int part = blockIdx.y;                 // 0..3
  const int n = p0 + lane;
  const int bimg = p0 / HWSZ;
  const int c8 = part * 64 + wid * 8;
  const float* xc0 = x + ((size_t)bimg * CI + c8) * HWSZ;

  uint_t pkw[36];
#pragma unroll
  for (int i = 0; i < 36; ++i) pkw[i] = 0u;

#pragma unroll
  for (int k = 0; k < 9; ++k) {
    uint_t o2 = offs[(size_t)k * NPIX + n];
    float4 wv = wts[(size_t)k * NPIX + n];
    const float* b0 = xc0 + (o2 & 0xffffu);
    const float* b1 = xc0 + (o2 >> 16);
    f32x2a a[8], b[8];
#pragma unroll
    for (int cl = 0; cl < 8; ++cl) {
      a[cl] = *(const f32x2a*)(b0 + cl * HWSZ);
      b[cl] = *(const f32x2a*)(b1 + cl * HWSZ);
    }
#pragma unroll
    for (int cl = 0; cl < 8; ++cl) {
      float v = wv.x * a[cl].x + wv.y * a[cl].y + wv.z * b[cl].x + wv.w * b[cl].y;
      const int q = 9 * cl + k;                // static
      pkw[q >> 1] |= ((uint_t)f2bf(v)) << ((q & 1) * 16);
    }
  }

  const size_t G0 = (size_t)9 * (part * 8 + wid);
#pragma unroll
  for (int g = 0; g < 9; ++g) {
    uint4 st = make_uint4(pkw[4 * g], pkw[4 * g + 1], pkw[4 * g + 2], pkw[4 * g + 3]);
    *(uint4*)&S_g[((G0 + g) * NPIX + n) * 8] = st;
  }
}

// ---------------- s_gemm: out = W9 * S + b_dcn ----------------
// BM=256, BN=64, BK=32, 72 chunks, grid 288, 512 thr / 8 waves, wave 64x32.
__global__ __launch_bounds__(512, 4) void s_gemm(
    const ushort_t* __restrict__ w9r, const ushort_t* __restrict__ S_g,
    const float* __restrict__ b_dcn, float* __restrict__ out) {
  __shared__ __align__(16) ushort_t A[2][8192];   // 32 KB
  __shared__ __align__(16) ushort_t S[2][2048];   // 8 KB

  const int tid = threadIdx.x;
  const int lane = tid & 63, wid = tid >> 6;
  const int p0 = blockIdx.x * 64;
  const int bimg = p0 / HWSZ;
  const int hw0 = p0 - bimg * HWSZ;
  const int lg = lane >> 4, lm = lane & 15;
  const int wr = wid >> 1, wc = wid & 1;

  f32x4 acc[4][2];
#pragma unroll
  for (int i = 0; i < 4; ++i)
#pragma unroll
    for (int j = 0; j < 2; ++j) acc[i][j] = (f32x4){0.f, 0.f, 0.f, 0.f};

#define SG_STAGE(CH, BUF)                                                     \
  {                                                                           \
    gload16(w9r + (size_t)(CH) * 8192 + tid * 8, &A[BUF][wid * 512]);         \
    gload16(w9r + (size_t)(CH) * 8192 + 4096 + tid * 8, &A[BUF][4096 + wid * 512]); \
    if (wid < 4)                                                              \
      gload16(S_g + ((size_t)((CH) * 4 + wid) * NPIX + p0 + lane) * 8,        \
              &S[BUF][wid * 512]);                                            \
  }
#define SG_MFMA(BUF)                                                          \
  {                                                                           \
    bf16x8 bfr0 = *(const bf16x8*)&S[BUF][(lg * 64 + wc * 32 + lm) * 8];      \
    bf16x8 bfr1 = *(const bf16x8*)&S[BUF][(lg * 64 + wc * 32 + 16 + lm) * 8]; \
    _Pragma("unroll") for (int mi = 0; mi < 4; ++mi) {                        \
      bf16x8 af = *(const bf16x8*)&A[BUF][(lg * 256 + wr * 64 + mi * 16 + lm) * 8]; \
      acc[mi][0] = __builtin_amdgcn_mfma_f32_16x16x32_bf16(af, bfr0, acc[mi][0], 0, 0, 0); \
      acc[mi][1] = __builtin_amdgcn_mfma_f32_16x16x32_bf16(af, bfr1, acc[mi][1], 0, 0, 0); \
    }                                                                         \
  }

  SG_STAGE(0, 0)
  for (int ko = 0; ko < 71; ++ko) {
    const int cur = ko & 1, nxt = cur ^ 1;
    SG_STAGE(ko + 1, nxt)
    if (wid < 4) { asm volatile("s_waitcnt vmcnt(3)" ::: "memory"); }
    else         { asm volatile("s_waitcnt vmcnt(2)" ::: "memory"); }
    __builtin_amdgcn_s_barrier();
    __builtin_amdgcn_sched_barrier(0);
    SG_MFMA(cur)
    asm volatile("s_waitcnt lgkmcnt(0)" ::: "memory");
    __builtin_amdgcn_s_barrier();
    __builtin_amdgcn_sched_barrier(0);
  }
  asm volatile("s_waitcnt vmcnt(0) lgkmcnt(0)" ::: "memory");
  __builtin_amdgcn_s_barrier();
  __builtin_amdgcn_sched_barrier(0);
  SG_MFMA(1)
#undef SG_STAGE
#undef SG_MFMA

  const int hwv0 = hw0 + wc * 32 + lm;
#pragma unroll
  for (int mi = 0; mi < 4; ++mi) {
    int obase = wr * 64 + mi * 16 + lg * 4;
#pragma unroll
    for (int ni = 0; ni < 2; ++ni)
#pragma unroll
      for (int r = 0; r < 4; ++r) {
        int o = obase + r;
        out[((size_t)(bimg * CO + o)) * HWSZ + hwv0 + ni * 16] = acc[mi][ni][r] + b_dcn[o];
      }
  }
}

// ---------------- fallback: R5 fused sample+GEMM (small ws) ----------------
__global__ __launch_bounds__(512, 4) void dcn_gemm(
    const float* __restrict__ x, const ushort_t* __restrict__ w9r,
    const uint_t* __restrict__ offs, const float4* __restrict__ wts,
    const float* __restrict__ b_dcn, float* __restrict__ out) {
  __shared__ __align__(16) ushort_t Alds[2][8192];
  __shared__ __align__(16) ushort_t Slds[1024];
  __shared__ uint_t off_l[9][32];
  __shared__ __align__(16) float4 wt_l[9][32];

  const int tid = threadIdx.x;
  const int p0 = blockIdx.x * 32;
  const int bimg = p0 / HWSZ;
  const int hw0 = p0 - bimg * HWSZ;
  const float* xb = x + (size_t)bimg * CI * HWSZ;

  for (int e = tid; e < 9 * 32; e += 512) {
    int k = e >> 5, p = e & 31;
    off_l[k][p] = offs[(size_t)k * NPIX + p0 + p];
    wt_l[k][p] = wts[(size_t)k * NPIX + p0 + p];
  }
  f32x4 acc[4];
#pragma unroll
  for (int i = 0; i < 4; ++i) acc[i] = (f32x4){0.f, 0.f, 0.f, 0.f};

  const int lane = tid & 63, wid = tid >> 6;
  const int wr = wid >> 1, wc = wid & 1;
  const int lg = lane >> 4, lm = lane & 15;
  const int sp = tid & 31;
  const int sk2 = tid >> 5;
  int cb, kb;
  { int kkb = sk2 * 2; cb = kkb / 9; kb = kkb - cb * 9; }

  __syncthreads();

  f32x2a r0[2], r1[2];
  {
    int c = cb, k = kb;
#pragma unroll
    for (int j = 0; j < 2; ++j) {
      uint_t o2 = off_l[k][sp];
      const float* xc = xb + c * HWSZ;
      r0[j] = *(const f32x2a*)(xc + (o2 & 0xffffu));
      r1[j] = *(const f32x2a*)(xc + (o2 >> 16));
      ++k; if (k == 9) { k = 0; ++c; }
    }
    const ushort_t* ga = w9r + tid * 8;
    gload16(ga, &Alds[0][wid * 512]);
    gload16(ga + 4096, &Alds[0][4096 + wid * 512]);
  }

  for (int ko = 0; ko < 71; ++ko) {
    const int cur = ko & 1, nxt = cur ^ 1;
    {
      float v[2];
      int k = kb;
#pragma unroll
      for (int j = 0; j < 2; ++j) {
        float4 wv = wt_l[k][sp];
        v[j] = wv.x * r0[j].x + wv.y * r0[j].y + wv.z * r1[j].x + wv.w * r1[j].y;
        ++k; if (k == 9) k = 0;
      }
      uint_t pk = (uint_t)f2bf(v[0]) | ((uint_t)f2bf(v[1]) << 16);
      *(uint_t*)&Slds[((sk2 >> 2) * 32 + sp) * 8 + (sk2 & 3) * 2] = pk;
    }
    {
      kb += 5; cb += 3;
      if (kb >= 9) { kb -= 9; ++cb; }
      int c = cb, k = kb;
#pragma unroll
      for (int j = 0; j < 2; ++j) {
        uint_t o2 = off_l[k][sp];
        const float* xc = xb + c * HWSZ;
        r0[j] = *(const f32x2a*)(xc + (o2 & 0xffffu));
        r1[j] = *(const f32x2a*)(xc + (o2 >> 16));
        ++k; if (k == 9) { k = 0; ++c; }
      }
      const ushort_t* ga = w9r + (size_t)(ko + 1) * 8192 + tid * 8;
      gload16(ga, &Alds[nxt][wid * 512]);
      gload16(ga + 4096, &Alds[nxt][4096 + wid * 512]);
    }
    asm volatile("s_waitcnt vmcnt(6) lgkmcnt(0)" ::: "memory");
    __builtin_amdgcn_s_barrier();
    __builtin_amdgcn_sched_barrier(0);
    {
      bf16x8 bfr = *(const bf16x8*)&Slds[(lg * 32 + wc * 16 + lm) * 8];
#pragma unroll
      for (int mi = 0; mi < 4; ++mi) {
        bf16x8 af = *(const bf16x8*)&Alds[cur][(lg * 256 + wr * 64 + mi * 16 + lm) * 8];
        acc[mi] = __builtin_amdgcn_mfma_f32_16x16x32_bf16(af, bfr, acc[mi], 0, 0, 0);
      }
    }
    asm volatile("s_waitcnt lgkmcnt(0)" ::: "memory");
    __builtin_amdgcn_s_barrier();
    __builtin_amdgcn_sched_barrier(0);
  }
  {
    {
      float v[2];
      int k = kb;
#pragma unroll
      for (int j = 0; j < 2; ++j) {
        float4 wv = wt_l[k][sp];
        v[j] = wv.x * r0[j].x + wv.y * r0[j].y + wv.z * r1[j].x + wv.w * r1[j].y;
        ++k; if (k == 9) k = 0;
      }
      uint_t pk = (uint_t)f2bf(v[0]) | ((uint_t)f2bf(v[1]) << 16);
      *(uint_t*)&Slds[((sk2 >> 2) * 32 + sp) * 8 + (sk2 & 3) * 2] = pk;
    }
    asm volatile("s_waitcnt vmcnt(0) lgkmcnt(0)" ::: "memory");
    __builtin_amdgcn_s_barrier();
    __builtin_amdgcn_sched_barrier(0);
    bf16x8 bfr = *(const bf16x8*)&Slds[(lg * 32 + wc * 16 + lm) * 8];
#pragma unroll
    for (int mi = 0; mi < 4; ++mi) {
      bf16x8 af = *(const bf16x8*)&Alds[1][(lg * 256 + wr * 64 + mi * 16 + lm) * 8];
      acc[mi] = __builtin_amdgcn_mfma_f32_16x16x32_bf16(af, bfr, acc[mi], 0, 0, 0);
    }
  }
  const int hwv = hw0 + wc * 16 + lm;
#pragma unroll
  for (int mi = 0; mi < 4; ++mi) {
    int obase = wr * 64 + mi * 16 + lg * 4;
#pragma unroll
    for (int r = 0; r < 4; ++r) {
      int o = obase + r;
      out[((size_t)(bimg * CO + o)) * HWSZ + hwv] = acc[mi][r] + b_dcn[o];
    }
  }
}

// ---------------- BN stats, two-stage ----------------
// stage 1: grid (256 ch, 4 slice); slice s: image s>>1, half s&1 (4608 px).
__global__ __launch_bounds__(256) void bn_stats1(const float* __restrict__ out,
                                                 float2* __restrict__ part) {
  int o = blockIdx.x, s = blockIdx.y, tid = threadIdx.x;
  const float4* p = (const float4*)(out + ((size_t)((s >> 1) * CO + o)) * HWSZ + (s & 1) * 4608);
  float sum = 0.f, sq = 0.f;
#pragma unroll
  for (int j = tid; j < 1152; j += 256) {
    float4 v = p[j];
    sum += v.x + v.y + v.z + v.w;
    sq += v.x * v.x + v.y * v.y + v.z * v.z + v.w * v.w;
  }
#pragma unroll
  for (int off = 32; off > 0; off >>= 1) {
    sum += __shfl_xor(sum, off);
    sq += __shfl_xor(sq, off);
  }
  __shared__ float rs[4], rq[4];
  if ((tid & 63) == 0) { rs[tid >> 6] = sum; rq[tid >> 6] = sq; }
  __syncthreads();
  if (tid == 0)
    part[o * 4 + s] = make_float2(rs[0] + rs[1] + rs[2] + rs[3],
                                  rq[0] + rq[1] + rq[2] + rq[3]);
}

// stage 2: one block, thread o finalizes channel o.
__global__ __launch_bounds__(256) void bn_finl(const float2* __restrict__ part,
                                               const float* __restrict__ gamma,
                                               const float* __restrict__ beta,
                                               float* __restrict__ ss) {
  int o = threadIdx.x;
  float s = 0.f, sq = 0.f;
#pragma unroll
  for (int i = 0; i < 4; ++i) {
    float2 p = part[o * 4 + i];
    s += p.x; sq += p.y;
  }
  float mean = s * (1.f / (float)NPIX);
  float var = sq * (1.f / (float)NPIX) - mean * mean;
  float rstd = rsqrtf(var + 1e-5f);
  float sc = rstd * gamma[o];
  ss[o] = sc;
  ss[CO + o] = beta[o] - mean * sc;
}

// ---------------- BN apply + ReLU ----------------
__global__ void bn_apply(float* __restrict__ out, const float* __restrict__ ss) {
  int i = blockIdx.x * 256 + threadIdx.x;
  float4 v = ((float4*)out)[i];
  int o = (i / (HWSZ / 4)) & 255;
  float sc = ss[o], sh = ss[CO + o];
  v.x = fmaxf(v.x * sc + sh, 0.f);
  v.y = fmaxf(v.y * sc + sh, 0.f);
  v.z = fmaxf(v.z * sc + sh, 0.f);
  v.w = fmaxf(v.w * sc + sh, 0.f);
  ((float4*)out)[i] = v;
}

extern "C" void kernel_launch(void* const* d_in, const int* in_sizes, int n_in,
                              void* d_out, int out_size, void* d_ws, size_t ws_size,
                              hipStream_t stream) {
  const float* x = (const float*)d_in[0];
  const float* w_off = (const float*)d_in[1];
  const float* b_off = (const float*)d_in[2];
  const float* w_dcn = (const float*)d_in[3];
  const float* b_dcn = (const float*)d_in[4];
  const float* gamma = (const float*)d_in[5];
  const float* beta = (const float*)d_in[6];
  float* out = (float*)d_out;

  char* ws = (char*)d_ws;
  const bool big = (ws_size >= (size_t)92 * 1024 * 1024);

  size_t base = big ? 84934656 : 0;            // S_g occupies [0, 84934656) if big
  ushort_t* S_g   = (ushort_t*)(ws);
  float*    om    = (float*)(ws + base);                    // 1,990,656
  uint_t*   offs  = (uint_t*)(ws + base + 1990656);         //   663,552
  float4*   wts   = (float4*)(ws + base + 2654208);         // 2,654,208
  ushort_t* w9r   = (ushort_t*)(ws + base + 5308416);       // 1,179,648
  ushort_t* w27r  = (ushort_t*)(ws + base + 6488064);       //   147,456
  float*    ss    = (float*)(ws + base + 6635520);          //     2,048
  float2*   bnp   = (float2*)(ws + base + 6637568);         //     8,192

  cvt_w9<<<(CO * KTOT) / 256, 256, 0, stream>>>(w_dcn, w9r);
  cvt_woff9<<<(32 * KTOT) / 256, 256, 0, stream>>>(w_off, w27r);
  off_gemm<<<NPIX / 64, 512, 0, stream>>>(x, w27r, om);
  prep_kernel<<<NPIX / 128, 128, 0, stream>>>(om, b_off, offs, wts);
  if (big) {
    sample_s<<<dim3(NPIX / 64, 4), 512, 0, stream>>>(x, offs, wts, S_g);
    s_gemm<<<NPIX / 64, 512, 0, stream>>>(w9r, S_g, b_dcn, out);
  } else {
    dcn_gemm<<<NPIX / 32, 512, 0, stream>>>(x, w9r, offs, wts, b_dcn, out);
  }
  bn_stats1<<<dim3(CO, 4), 256, 0, stream>>>(out, bnp);
  bn_finl<<<1, 256, 0, stream>>>(bnp, gamma, beta, ss);
  bn_apply<<<(out_size / 4) / 256, 256, 0, stream>>>(out, ss);
}

// Round 10
// 204.757 us; speedup vs baseline: 1.1825x; 1.1825x over previous
//
#include <hip/hip_runtime.h>

// DeformConv fused pipeline, MI355X gfx950. Shapes: B=2, Ci=Co=256, H=W=96.
// R10 changes vs R9 (sample_s regressed 100->122us: k-outer killed 9-tap L1
// locality, FETCH 89->157MB; VGPR=64 forced table remat):
//  - sample_s: back to c-inner (L1-friendly) + EXPLICIT depth-2 channel
//    pipeline with named reg buffers (rule #20), launch_bounds(512,2).
//  - off_gemm: counted vmcnt(10/9) pipeline (raw-B regs depth-2, A gload_lds
//    dbuf), K-split over blockIdx.y -> 576 blocks; om_part[2] summed in prep.

typedef unsigned short ushort_t;
typedef unsigned int uint_t;
typedef __attribute__((ext_vector_type(8))) short bf16x8;
typedef __attribute__((ext_vector_type(4))) float f32x4;
typedef __attribute__((ext_vector_type(2), aligned(4))) float f32x2a;

#define HH 96
#define WW 96
#define HWSZ 9216
#define CI 256
#define CO 256
#define NB 2
#define NPIX 18432
#define KTOT 2304

__device__ __forceinline__ ushort_t f2bf(float f) {
  unsigned int u = __float_as_uint(f);
  u += 0x7fffu + ((u >> 16) & 1u);
  return (ushort_t)(u >> 16);
}
__device__ __forceinline__ float u2f(uint_t u) { return __uint_as_float(u); }

__device__ __forceinline__ void gload16(const void* g, void* l) {
  __builtin_amdgcn_global_load_lds(
      (const __attribute__((address_space(1))) unsigned int*)g,
      (__attribute__((address_space(3))) unsigned int*)l, 16, 0, 0);
}

// ---------------- cvt_w9: w_dcn -> bf16 [kk>>3][m][kk&7] ----------------
__global__ void cvt_w9(const float* __restrict__ w, ushort_t* __restrict__ o) {
  int i = blockIdx.x * 256 + threadIdx.x;      // grid exact CO*KTOT
  int oo = i / KTOT;
  int kk = i - oo * KTOT;
  o[(kk >> 3) * 2048 + oo * 8 + (kk & 7)] = f2bf(w[i]);
}

// ---------------- cvt_woff9: w_off -> bf16 [kk>>3][m32][kk&7], rows>=27 zero ----
__global__ void cvt_woff9(const float* __restrict__ w, ushort_t* __restrict__ o) {
  int i = blockIdx.x * 256 + threadIdx.x;      // grid exact 32*KTOT
  int m = i / KTOT;
  int kk = i - m * KTOT;
  float v = (m < 27) ? w[m * KTOT + kk] : 0.f;
  o[(kk >> 3) * 256 + m * 8 + (kk & 7)] = f2bf(v);
}

// ---------------- off_gemm: om_part[part][27][NPIX], K-split halves ----------------
// Grid (288, 2). 18 chunks/block. Counted-vmcnt pipeline: raw-B depth-2 regs,
// A27 gload_lds dbuf. Queue/wave: raw(ko)8, gA(ko)1, raw(ko+1)8, gA(ko+1)1.
__global__ __launch_bounds__(512, 2) void off_gemm(
    const float* __restrict__ x, const ushort_t* __restrict__ w27r,
    float* __restrict__ om_part) {
  __shared__ __align__(16) ushort_t A27[2][2048];
  __shared__ __align__(16) ushort_t B64[4096];
  __shared__ uint2 tbl[9][64];                 // {abs idx (0 if invalid), mask}

  const int tid = threadIdx.x;
  const int lane = tid & 63, wid = tid >> 6;
  const int p0 = blockIdx.x * 64;
  const int part = blockIdx.y;                 // K half
  const int bimg = p0 / HWSZ;
  const int hw0 = p0 - bimg * HWSZ;
  const float* xb = x + (size_t)bimg * CI * HWSZ;

  for (int e = tid; e < 576; e += 512) {
    int k = e >> 6, px = e & 63;
    int hw = hw0 + px, h = hw / WW, w_ = hw - h * WW;
    int dy = k / 3 - 1, dx = k % 3 - 1;
    bool ok = (h + dy >= 0) && (h + dy < HH) && (w_ + dx >= 0) && (w_ + dx < WW);
    tbl[k][px] = make_uint2(ok ? (uint_t)(hw + dy * WW + dx) : 0u,
                            ok ? 0x3f800000u : 0u);
  }

  const int lg = lane >> 4, lm = lane & 15;
  const int wr = wid >> 2, wc = wid & 3;
  f32x4 acc = (f32x4){0.f, 0.f, 0.f, 0.f};

  int cj[8], kj[8];
#pragma unroll
  for (int j = 0; j < 8; ++j) {
    int kk = part * 1152 + wid * 8 + j;
    cj[j] = kk / 9;
    kj[j] = kk - 9 * cj[j];
  }
  __syncthreads();

  float rv0[8], rm0[8], rv1[8], rm1[8];
  const int k0 = part * 18;

#define OG_RAW(RV, RM)                                                        \
  { _Pragma("unroll") for (int j = 0; j < 8; ++j) {                           \
      uint2 e_ = tbl[kj[j]][lane];                                            \
      RV[j] = xb[cj[j] * HWSZ + (int)e_.x];                                   \
      RM[j] = u2f(e_.y);                                                      \
      kj[j] += 1; cj[j] += 7;                                                 \
      if (kj[j] == 9) { kj[j] = 0; cj[j] += 1; } } }
#define OG_GA(CH, BUF)                                                        \
  gload16(w27r + (size_t)(CH) * 2048 + (tid & 255) * 8, &A27[BUF][(wid & 3) * 512]);
#define OG_STEP(CUR, RVC, RMC, RVN, RMN, KO)                                  \
  {                                                                           \
    if ((KO) < 17) {                                                          \
      OG_RAW(RVN, RMN)                                                        \
      OG_GA(k0 + (KO) + 1, (CUR) ^ 1)                                         \
      asm volatile("s_waitcnt vmcnt(10)" ::: "memory");                       \
    } else {                                                                  \
      asm volatile("s_waitcnt vmcnt(1)" ::: "memory");                        \
    }                                                                         \
    __builtin_amdgcn_sched_barrier(0);                                        \
    {                                                                         \
      ushort_t sv_[8] __attribute__((aligned(16)));                           \
      _Pragma("unroll") for (int j = 0; j < 8; ++j)                           \
        sv_[j] = f2bf(RVC[j] * RMC[j]);                                       \
      *(uint4*)&B64[tid * 8] = *(const uint4*)sv_;                            \
    }                                                                         \
    if ((KO) < 17) asm volatile("s_waitcnt vmcnt(9) lgkmcnt(0)" ::: "memory"); \
    else           asm volatile("s_waitcnt vmcnt(0) lgkmcnt(0)" ::: "memory"); \
    __builtin_amdgcn_s_barrier();                                             \
    __builtin_amdgcn_sched_barrier(0);                                        \
    _Pragma("unroll") for (int s = 0; s < 2; ++s) {                           \
      bf16x8 af = *(const bf16x8*)&A27[CUR][((s * 4 + lg) * 32 + wr * 16 + lm) * 8]; \
      bf16x8 bfv = *(const bf16x8*)&B64[((s * 4 + lg) * 64 + wc * 16 + lm) * 8];     \
      acc = __builtin_amdgcn_mfma_f32_16x16x32_bf16(af, bfv, acc, 0, 0, 0);   \
    }                                                                         \
    asm volatile("s_waitcnt lgkmcnt(0)" ::: "memory");                        \
    __builtin_amdgcn_s_barrier();                                             \
    __builtin_amdgcn_sched_barrier(0);                                        \
  }

  OG_RAW(rv0, rm0)
  OG_GA(k0, 0)
  for (int ko2 = 0; ko2 < 9; ++ko2) {
    const int ko = ko2 * 2;
    OG_STEP(0, rv0, rm0, rv1, rm1, ko)
    OG_STEP(1, rv1, rm1, rv0, rm0, ko + 1)
  }
#undef OG_RAW
#undef OG_GA
#undef OG_STEP

  int row = wr * 16 + lg * 4;
  int col = p0 + wc * 16 + lm;
#pragma unroll
  for (int r = 0; r < 4; ++r)
    if (row + r < 27)
      om_part[((size_t)(part * 27 + row + r)) * NPIX + col] = acc[r];
}

// ---------------- prep: sum om halves -> row-pair offsets + folded weights ----------------
__global__ void prep_kernel(const float* __restrict__ om_part, const float* __restrict__ b_off,
                            uint_t* __restrict__ offs, float4* __restrict__ wts) {
  int n = blockIdx.x * 128 + threadIdx.x;      // grid 144 x 128
  float omv[27];
#pragma unroll
  for (int ch = 0; ch < 27; ++ch)
    omv[ch] = b_off[ch] + om_part[(size_t)ch * NPIX + n] +
              om_part[((size_t)(27 + ch)) * NPIX + n];
  int hw = n % HWSZ;
  int h = hw / WW, w = hw - h * WW;
#pragma unroll
  for (int k = 0; k < 9; ++k) {
    float dy = omv[2 * k], dx = omv[2 * k + 1];
    float mk = 1.f / (1.f + __expf(-omv[18 + k]));
    float py = dy + (float)(h - 1 + k / 3);
    float px = dx + (float)(w - 1 + k % 3);
    float y0f = floorf(py), x0f = floorf(px);
    int y0 = (int)y0f, x0 = (int)x0f;
    float wy1 = py - y0f, wx1 = px - x0f;
    float wy0 = 1.f - wy1, wx0 = 1.f - wx1;
    float vy0 = (y0 >= 0 && y0 <= HH - 1) ? 1.f : 0.f;
    float vy1 = (y0 + 1 >= 0 && y0 + 1 <= HH - 1) ? 1.f : 0.f;
    int yc0 = min(max(y0, 0), HH - 1), yc1 = min(max(y0 + 1, 0), HH - 1);
    int xa = min(max(x0, 0), WW - 2);
    float a_, b_;
    if (x0 >= 0 && x0 <= WW - 2)      { a_ = wx0; b_ = wx1; }
    else if (x0 == -1)                { a_ = wx1; b_ = 0.f; }
    else if (x0 == WW - 1)            { a_ = 0.f; b_ = wx0; }
    else                              { a_ = 0.f; b_ = 0.f; }
    float s0 = mk * vy0 * wy0, s1 = mk * vy1 * wy1;
    offs[(size_t)k * NPIX + n] = (uint_t)(yc0 * WW + xa) | ((uint_t)(yc1 * WW + xa) << 16);
    wts[(size_t)k * NPIX + n] = make_float4(a_ * s0, b_ * s0, a_ * s1, b_ * s1);
  }
}

// ---------------- sample_s: S_g[kk>>3][n][kk&7] bf16, c-major kk ----------------
// Grid 288 x 4 (channel quarters); wave = 8 channels. c-INNER taps (L1 reuse)
// + explicit depth-2 channel pipeline (named reg buffers, static indices).
__global__ __launch_bounds__(512, 2) void sample_s(
    const float* __restrict__ x, const uint_t* __restrict__ offs,
    const float4* __restrict__ wts, ushort_t* __restrict__ S_g) {
  const int tid = threadIdx.x;
  const int lane = tid & 63, wid = tid >> 6;
  const int p0 = blockIdx.x * 64;
  const int part = blockIdx.y;                 // 0..3
  const int n = p0 + lane;
  const int bimg = p0 / HWSZ;
  const int c8 = part * 64 + wid * 8;
  const float* xc0 = x + ((size_t)bimg * CI + c8) * HWSZ;

  uint_t ofr[9]; float4 wtr[9];
#pragma unroll
  for (int k = 0; k < 9; ++k) {
    ofr[k] = offs[(size_t)k * NPIX + n];
    wtr[k] = wts[(size_t)k * NPIX + n];
  }

  uint_t pkw[36];
#pragma unroll
  for (int i = 0; i < 36; ++i) pkw[i] = 0u;

  f32x2a a0[9], b0[9], a1[9], b1[9];

#define SLOAD(A_, B_, CL)                                                     \
  { const float* xc_ = xc0 + (CL) * HWSZ;                                     \
    _Pragma("unroll") for (int k = 0; k < 9; ++k) {                           \
      A_[k] = *(const f32x2a*)(xc_ + (ofr[k] & 0xffffu));                     \
      B_[k] = *(const f32x2a*)(xc_ + (ofr[k] >> 16)); } }
#define SCONS(A_, B_, CL)                                                     \
  { _Pragma("unroll") for (int k = 0; k < 9; ++k) {                           \
      float v_ = wtr[k].x * A_[k].x + wtr[k].y * A_[k].y +                    \
                 wtr[k].z * B_[k].x + wtr[k].w * B_[k].y;                     \
      const int q_ = 9 * (CL) + k;                                            \
      pkw[q_ >> 1] |= ((uint_t)f2bf(v_)) << ((q_ & 1) * 16); } }

  SLOAD(a0, b0, 0)
  SLOAD(a1, b1, 1)
  SCONS(a0, b0, 0)
  SLOAD(a0, b0, 2)
  SCONS(a1, b1, 1)
  SLOAD(a1, b1, 3)
  SCONS(a0, b0, 2)
  SLOAD(a0, b0, 4)
  SCONS(a1, b1, 3)
  SLOAD(a1, b1, 5)
  SCONS(a0, b0, 4)
  SLOAD(a0, b0, 6)
  SCONS(a1, b1, 5)
  SLOAD(a1, b1, 7)
  SCONS(a0, b0, 6)
  SCONS(a1, b1, 7)
#undef SLOAD
#undef SCONS

  const size_t G0 = (size_t)9 * (part * 8 + wid);
#pragma unroll
  for (int g = 0; g < 9; ++g) {
    uint4 st = make_uint4(pkw[4 * g], pkw[4 * g + 1], pkw[4 * g + 2], pkw[4 * g + 3]);
    *(uint4*)&S_g[((G0 + g) * NPIX + n) * 8] = st;
  }
}

// ---------------- s_gemm: out = W9 * S + b_dcn ----------------
// BM=256, BN=64, BK=32, 72 chunks, grid 288, 512 thr / 8 waves, wave 64x32.
__global__ __launch_bounds__(512, 4) void s_gemm(
    const ushort_t* __restrict__ w9r, const ushort_t* __restrict__ S_g,
    const float* __restrict__ b_dcn, float* __restrict__ out) {
  __shared__ __align__(16) ushort_t A[2][8192];   // 32 KB
  __shared__ __align__(16) ushort_t S[2][2048];   // 8 KB

  const int tid = threadIdx.x;
  const int lane = tid & 63, wid = tid >> 6;
  const int p0 = blockIdx.x * 64;
  const int bimg = p0 / HWSZ;
  const int hw0 = p0 - bimg * HWSZ;
  const int lg = lane >> 4, lm = lane & 15;
  const int wr = wid >> 1, wc = wid & 1;

  f32x4 acc[4][2];
#pragma unroll
  for (int i = 0; i < 4; ++i)
#pragma unroll
    for (int j = 0; j < 2; ++j) acc[i][j] = (f32x4){0.f, 0.f, 0.f, 0.f};

#define SG_STAGE(CH, BUF)                                                     \
  {                                                                           \
    gload16(w9r + (size_t)(CH) * 8192 + tid * 8, &A[BUF][wid * 512]);         \
    gload16(w9r + (size_t)(CH) * 8192 + 4096 + tid * 8, &A[BUF][4096 + wid * 512]); \
    if (wid < 4)                                                              \
      gload16(S_g + ((size_t)((CH) * 4 + wid) * NPIX + p0 + lane) * 8,        \
              &S[BUF][wid * 512]);                                            \
  }
#define SG_MFMA(BUF)                                                          \
  {                                                                           \
    bf16x8 bfr0 = *(const bf16x8*)&S[BUF][(lg * 64 + wc * 32 + lm) * 8];      \
    bf16x8 bfr1 = *(const bf16x8*)&S[BUF][(lg * 64 + wc * 32 + 16 + lm) * 8]; \
    _Pragma("unroll") for (int mi = 0; mi < 4; ++mi) {                        \
      bf16x8 af = *(const bf16x8*)&A[BUF][(lg * 256 + wr * 64 + mi * 16 + lm) * 8]; \
      acc[mi][0] = __builtin_amdgcn_mfma_f32_16x16x32_bf16(af, bfr0, acc[mi][0], 0, 0, 0); \
      acc[mi][1] = __builtin_amdgcn_mfma_f32_16x16x32_bf16(af, bfr1, acc[mi][1], 0, 0, 0); \
    }                                                                         \
  }

  SG_STAGE(0, 0)
  for (int ko = 0; ko < 71; ++ko) {
    const int cur = ko & 1, nxt = cur ^ 1;
    SG_STAGE(ko + 1, nxt)
    if (wid < 4) { asm volatile("s_waitcnt vmcnt(3)" ::: "memory"); }
    else         { asm volatile("s_waitcnt vmcnt(2)" ::: "memory"); }
    __builtin_amdgcn_s_barrier();
    __builtin_amdgcn_sched_barrier(0);
    SG_MFMA(cur)
    asm volatile("s_waitcnt lgkmcnt(0)" ::: "memory");
    __builtin_amdgcn_s_barrier();
    __builtin_amdgcn_sched_barrier(0);
  }
  asm volatile("s_waitcnt vmcnt(0) lgkmcnt(0)" ::: "memory");
  __builtin_amdgcn_s_barrier();
  __builtin_amdgcn_sched_barrier(0);
  SG_MFMA(1)
#undef SG_STAGE
#undef SG_MFMA

  const int hwv0 = hw0 + wc * 32 + lm;
#pragma unroll
  for (int mi = 0; mi < 4; ++mi) {
    int obase = wr * 64 + mi * 16 + lg * 4;
#pragma unroll
    for (int ni = 0; ni < 2; ++ni)
#pragma unroll
      for (int r = 0; r < 4; ++r) {
        int o = obase + r;
        out[((size_t)(bimg * CO + o)) * HWSZ + hwv0 + ni * 16] = acc[mi][ni][r] + b_dcn[o];
      }
  }
}

// ---------------- BN stats, two-stage ----------------
__global__ __launch_bounds__(256) void bn_stats1(const float* __restrict__ out,
                                                 float2* __restrict__ part) {
  int o = blockIdx.x, s = blockIdx.y, tid = threadIdx.x;
  const float4* p = (const float4*)(out + ((size_t)((s >> 1) * CO + o)) * HWSZ + (s & 1) * 4608);
  float sum = 0.f, sq = 0.f;
#pragma unroll
  for (int j = tid; j < 1152; j += 256) {
    float4 v = p[j];
    sum += v.x + v.y + v.z + v.w;
    sq += v.x * v.x + v.y * v.y + v.z * v.z + v.w * v.w;
  }
#pragma unroll
  for (int off = 32; off > 0; off >>= 1) {
    sum += __shfl_xor(sum, off);
    sq += __shfl_xor(sq, off);
  }
  __shared__ float rs[4], rq[4];
  if ((tid & 63) == 0) { rs[tid >> 6] = sum; rq[tid >> 6] = sq; }
  __syncthreads();
  if (tid == 0)
    part[o * 4 + s] = make_float2(rs[0] + rs[1] + rs[2] + rs[3],
                                  rq[0] + rq[1] + rq[2] + rq[3]);
}

__global__ __launch_bounds__(256) void bn_finl(const float2* __restrict__ part,
                                               const float* __restrict__ gamma,
                                               const float* __restrict__ beta,
                                               float* __restrict__ ss) {
  int o = threadIdx.x;
  float s = 0.f, sq = 0.f;
#pragma unroll
  for (int i = 0; i < 4; ++i) {
    float2 p = part[o * 4 + i];
    s += p.x; sq += p.y;
  }
  float mean = s * (1.f / (float)NPIX);
  float var = sq * (1.f / (float)NPIX) - mean * mean;
  float rstd = rsqrtf(var + 1e-5f);
  float sc = rstd * gamma[o];
  ss[o] = sc;
  ss[CO + o] = beta[o] - mean * sc;
}

// ---------------- BN apply + ReLU ----------------
__global__ void bn_apply(float* __restrict__ out, const float* __restrict__ ss) {
  int i = blockIdx.x * 256 + threadIdx.x;
  float4 v = ((float4*)out)[i];
  int o = (i / (HWSZ / 4)) & 255;
  float sc = ss[o], sh = ss[CO + o];
  v.x = fmaxf(v.x * sc + sh, 0.f);
  v.y = fmaxf(v.y * sc + sh, 0.f);
  v.z = fmaxf(v.z * sc + sh, 0.f);
  v.w = fmaxf(v.w * sc + sh, 0.f);
  ((float4*)out)[i] = v;
}

extern "C" void kernel_launch(void* const* d_in, const int* in_sizes, int n_in,
                              void* d_out, int out_size, void* d_ws, size_t ws_size,
                              hipStream_t stream) {
  const float* x = (const float*)d_in[0];
  const float* w_off = (const float*)d_in[1];
  const float* b_off = (const float*)d_in[2];
  const float* w_dcn = (const float*)d_in[3];
  const float* b_dcn = (const float*)d_in[4];
  const float* gamma = (const float*)d_in[5];
  const float* beta = (const float*)d_in[6];
  float* out = (float*)d_out;

  char* ws = (char*)d_ws;

  size_t base = 84934656;                      // S_g occupies [0, base)
  ushort_t* S_g   = (ushort_t*)(ws);
  float*    om    = (float*)(ws + base);                    // 2*27*NPIX*4 = 3,981,312
  uint_t*   offs  = (uint_t*)(ws + base + 3981312);         //   663,552
  float4*   wts   = (float4*)(ws + base + 4644864);         // 2,654,208
  ushort_t* w9r   = (ushort_t*)(ws + base + 7299072);       // 1,179,648
  ushort_t* w27r  = (ushort_t*)(ws + base + 8478720);       //   147,456
  float*    ss    = (float*)(ws + base + 8626176);          //     2,048
  float2*   bnp   = (float2*)(ws + base + 8628224);         //     8,192

  cvt_w9<<<(CO * KTOT) / 256, 256, 0, stream>>>(w_dcn, w9r);
  cvt_woff9<<<(32 * KTOT) / 256, 256, 0, stream>>>(w_off, w27r);
  off_gemm<<<dim3(NPIX / 64, 2), 512, 0, stream>>>(x, w27r, om);
  prep_kernel<<<NPIX / 128, 128, 0, stream>>>(om, b_off, offs, wts);
  sample_s<<<dim3(NPIX / 64, 4), 512, 0, stream>>>(x, offs, wts, S_g);
  s_gemm<<<NPIX / 64, 512, 0, stream>>>(w9r, S_g, b_dcn, out);
  bn_stats1<<<dim3(CO, 4), 256, 0, stream>>>(out, bnp);
  bn_finl<<<1, 256, 0, stream>>>(bnp, gamma, beta, ss);
  bn_apply<<<(out_size / 4) / 256, 256, 0, stream>>>(out, ss);
}